// Round 1
// baseline (534.268 us; speedup 1.0000x reference)
//
#include <hip/hip_runtime.h>

// KNN argmin over L2 distances: d2[q][s] = |q|^2 + |s|^2 - 2 q.s
// NQ = NS = 16384, D = 64, NCLASSES = 64, all fp32.
//
// Pipeline:
//   k_transpose_sq : [n][64] -> [64][n] transposed copy in ws + row sum-of-squares
//   k_argmin       : tiled 64q x 64s fp32 dot + fused argmin (4-way support split)
//   k_select       : reduce 4 split candidates, gather label via argmax of onehot row
//   k_writeout     : coalesced one-hot write of d_out
//
// Tie-break fidelity: reference argmin picks the FIRST minimal index. All
// min-updates here use strict < while scanning support indices in ascending
// order (j within thread, ty across threads, chunk, split) so the first
// minimum always wins, matching np.argmin.

#define NTOT   16384
#define DIM    64
#define NSPLIT 4
#define SPB    (NTOT / NSPLIT)   // supports per k_argmin block: 4096
#define FLT_BIG 3.4e38f

// ---------------------------------------------------------------------------
// Transpose [nrows][64] -> [64][nrows] and compute per-row sum of squares.
// block = 256 threads (logical 64 x 4), grid.x = nrows/64.
__global__ __launch_bounds__(256) void k_transpose_sq(
    const float* __restrict__ in, float* __restrict__ outT,
    float* __restrict__ sq) {
  __shared__ float tile[64][65];  // +1 pad: conflict-free transposed reads
  const int tx = threadIdx.x & 63;
  const int ty = threadIdx.x >> 6;
  const int rbase = blockIdx.x * 64;

#pragma unroll
  for (int i = 0; i < 16; ++i) {
    const int r = i * 4 + ty;
    tile[r][tx] = in[(rbase + r) * DIM + tx];  // coalesced 256B per wave
  }
  __syncthreads();
#pragma unroll
  for (int i = 0; i < 16; ++i) {
    const int d = i * 4 + ty;
    outT[d * NTOT + rbase + tx] = tile[tx][d];  // coalesced, LDS conflict-free
  }
  if (threadIdx.x < 64) {
    float s = 0.0f;
#pragma unroll
    for (int d = 0; d < DIM; ++d) {
      const float v = tile[threadIdx.x][d];
      s = fmaf(v, v, s);
    }
    sq[rbase + threadIdx.x] = s;
  }
}

// ---------------------------------------------------------------------------
// Main kernel: block handles 64 queries x SPB supports.
// grid = (NTOT/64, NSPLIT), block = 256 (tx = tid&15 -> 4 queries each,
// ty = tid>>4 -> 4 supports each per 64-support chunk).
__global__ __launch_bounds__(256) void k_argmin(
    const float* __restrict__ S_T, const float* __restrict__ Q_T,
    const float* __restrict__ sqS, const float* __restrict__ sqQ,
    float* __restrict__ cand_d2, int* __restrict__ cand_idx) {
  // sQ: 4096 floats [d][q], sS: 4096 floats [d][s], sqs: 64 floats.
  // reduction arrays reuse the sQ region after the chunk loop.
  __shared__ __align__(16) float smem[4096 + 4096 + 64];
  float* const sQ = smem;
  float* const sS = smem + 4096;
  float* const sqs_sh = smem + 8192;

  const int tid = threadIdx.x;
  const int tx = tid & 15;
  const int ty = tid >> 4;
  const int qbase = blockIdx.x * 64;
  const int sbase0 = blockIdx.y * SPB;

  // Stage Q tile [64 d][64 q] from Q_T (4 x 256B segments per wave, b128 LDS writes)
#pragma unroll
  for (int i = 0; i < 4; ++i) {
    const int j = i * 256 + tid;
    const int d = j >> 4;
    const int c = (j & 15) << 2;
    *(float4*)&sQ[d * 64 + c] = *(const float4*)&Q_T[d * NTOT + qbase + c];
  }

  float sqq[4];
#pragma unroll
  for (int i = 0; i < 4; ++i) sqq[i] = sqQ[qbase + tx * 4 + i];

  float best[4] = {FLT_BIG, FLT_BIG, FLT_BIG, FLT_BIG};
  int bix[4] = {0, 0, 0, 0};

  for (int chunk = 0; chunk < SPB / 64; ++chunk) {
    const int sb = sbase0 + chunk * 64;
    __syncthreads();  // previous chunk's readers done before restaging sS
#pragma unroll
    for (int i = 0; i < 4; ++i) {
      const int j = i * 256 + tid;
      const int d = j >> 4;
      const int c = (j & 15) << 2;
      *(float4*)&sS[d * 64 + c] = *(const float4*)&S_T[d * NTOT + sb + c];
    }
    if (tid < 64) sqs_sh[tid] = sqS[sb + tid];
    __syncthreads();

    float acc[4][4] = {{0.f, 0.f, 0.f, 0.f}, {0.f, 0.f, 0.f, 0.f},
                       {0.f, 0.f, 0.f, 0.f}, {0.f, 0.f, 0.f, 0.f}};
#pragma unroll
    for (int k = 0; k < DIM; ++k) {
      const float4 qv = *(const float4*)&sQ[k * 64 + tx * 4];  // 2-way (free)
      const float4 sv = *(const float4*)&sS[k * 64 + ty * 4];  // broadcast
      acc[0][0] = fmaf(qv.x, sv.x, acc[0][0]);
      acc[0][1] = fmaf(qv.x, sv.y, acc[0][1]);
      acc[0][2] = fmaf(qv.x, sv.z, acc[0][2]);
      acc[0][3] = fmaf(qv.x, sv.w, acc[0][3]);
      acc[1][0] = fmaf(qv.y, sv.x, acc[1][0]);
      acc[1][1] = fmaf(qv.y, sv.y, acc[1][1]);
      acc[1][2] = fmaf(qv.y, sv.z, acc[1][2]);
      acc[1][3] = fmaf(qv.y, sv.w, acc[1][3]);
      acc[2][0] = fmaf(qv.z, sv.x, acc[2][0]);
      acc[2][1] = fmaf(qv.z, sv.y, acc[2][1]);
      acc[2][2] = fmaf(qv.z, sv.z, acc[2][2]);
      acc[2][3] = fmaf(qv.z, sv.w, acc[2][3]);
      acc[3][0] = fmaf(qv.w, sv.x, acc[3][0]);
      acc[3][1] = fmaf(qv.w, sv.y, acc[3][1]);
      acc[3][2] = fmaf(qv.w, sv.z, acc[3][2]);
      acc[3][3] = fmaf(qv.w, sv.w, acc[3][3]);
    }

    // Fused argmin epilogue: ascending j => strict < keeps first minimum.
#pragma unroll
    for (int jj = 0; jj < 4; ++jj) {
      const float sqs_j = sqs_sh[ty * 4 + jj];
      const int sidx = sb + ty * 4 + jj;
#pragma unroll
      for (int i = 0; i < 4; ++i) {
        const float d2 = fmaf(-2.0f, acc[i][jj], sqq[i] + sqs_j);
        const bool u = d2 < best[i];
        best[i] = u ? d2 : best[i];
        bix[i] = u ? sidx : bix[i];
      }
    }
  }

  // Cross-ty reduction (16 candidates per query). Reuse sQ region.
  __syncthreads();
  float* const red_d2 = sQ;            // 64*16 floats
  int* const red_ix = (int*)(sQ + 1024);
#pragma unroll
  for (int i = 0; i < 4; ++i) {
    const int q = tx * 4 + i;
    red_d2[q * 16 + ty] = best[i];
    red_ix[q * 16 + ty] = bix[i];
  }
  __syncthreads();
  if (tid < 64) {
    float bd = red_d2[tid * 16];
    int bi = red_ix[tid * 16];
#pragma unroll
    for (int t = 1; t < 16; ++t) {  // ascending ty => ascending support index
      const float d = red_d2[tid * 16 + t];
      const int ix = red_ix[tid * 16 + t];
      const bool u = d < bd;
      bd = u ? d : bd;
      bi = u ? ix : bi;
    }
    cand_d2[blockIdx.y * NTOT + qbase + tid] = bd;
    cand_idx[blockIdx.y * NTOT + qbase + tid] = bi;
  }
}

// ---------------------------------------------------------------------------
// Reduce splits (ascending => strict < keeps lowest support index on ties),
// then label = argmax (first max) of the winning support's onehot row.
__global__ __launch_bounds__(256) void k_select(
    const float* __restrict__ cand_d2, const int* __restrict__ cand_idx,
    const float* __restrict__ onehot, int* __restrict__ labels_pred) {
  const int q = blockIdx.x * 256 + threadIdx.x;
  float bd = cand_d2[q];
  int bi = cand_idx[q];
#pragma unroll
  for (int s = 1; s < NSPLIT; ++s) {
    const float d = cand_d2[s * NTOT + q];
    const int ix = cand_idx[s * NTOT + q];
    const bool u = d < bd;
    bd = u ? d : bd;
    bi = u ? ix : bi;
  }
  float mv = onehot[bi * 64];
  int mc = 0;
#pragma unroll
  for (int c = 1; c < 64; ++c) {
    const float v = onehot[bi * 64 + c];
    const bool u = v > mv;  // strict > => first max, matches np.argmax
    mv = u ? v : mv;
    mc = u ? c : mc;
  }
  labels_pred[q] = mc;
}

// ---------------------------------------------------------------------------
__global__ __launch_bounds__(256) void k_writeout(
    const int* __restrict__ labels_pred, float* __restrict__ out) {
  const int t = blockIdx.x * 256 + threadIdx.x;  // NTOT*64 total
  const int q = t >> 6;
  const int c = t & 63;
  out[t] = (c == labels_pred[q]) ? 1.0f : 0.0f;
}

// ---------------------------------------------------------------------------
extern "C" void kernel_launch(void* const* d_in, const int* in_sizes, int n_in,
                              void* d_out, int out_size, void* d_ws, size_t ws_size,
                              hipStream_t stream) {
  const float* S = (const float*)d_in[0];   // support_embeddings [16384][64]
  const float* Q = (const float*)d_in[1];   // query_embeddings   [16384][64]
  const float* OH = (const float*)d_in[2];  // support_labels_onehot [16384][64]
  float* out = (float*)d_out;               // [16384][64] fp32

  char* ws = (char*)d_ws;
  float* S_T = (float*)ws;                                   // 4 MB
  float* Q_T = (float*)(ws + (4u << 20));                    // 4 MB
  float* sqS = (float*)(ws + (8u << 20));                    // 64 KB
  float* sqQ = (float*)(ws + (8u << 20) + (64u << 10));      // 64 KB
  float* cd2 = (float*)(ws + (8u << 20) + (128u << 10));     // 256 KB
  int* cix = (int*)(ws + (8u << 20) + (384u << 10));         // 256 KB
  int* lp = (int*)(ws + (8u << 20) + (640u << 10));          // 64 KB

  k_transpose_sq<<<dim3(NTOT / 64), 256, 0, stream>>>(S, S_T, sqS);
  k_transpose_sq<<<dim3(NTOT / 64), 256, 0, stream>>>(Q, Q_T, sqQ);
  k_argmin<<<dim3(NTOT / 64, NSPLIT), 256, 0, stream>>>(S_T, Q_T, sqS, sqQ, cd2, cix);
  k_select<<<dim3(NTOT / 256), 256, 0, stream>>>(cd2, cix, OH, lp);
  k_writeout<<<dim3(NTOT * 64 / 256), 256, 0, stream>>>(lp, out);
  (void)in_sizes; (void)n_in; (void)out_size; (void)ws_size;
}